// Round 6
// baseline (67.717 us; speedup 1.0000x reference)
//
#include <hip/hip_runtime.h>

#define NB 8192
#define NT 64
#define FCAP 5.0f

typedef unsigned int u32;
typedef float f32x4 __attribute__((ext_vector_type(4)));
typedef __bf16 bf16x8 __attribute__((ext_vector_type(8)));
typedef u32 u32x4 __attribute__((ext_vector_type(4)));
typedef u32 u32x2 __attribute__((ext_vector_type(2)));

static __device__ __forceinline__ u32 pk2(float lo, float hi) {
  u32 r;
  asm("v_cvt_pk_bf16_f32 %0, %1, %2" : "=v"(r) : "v"(lo), "v"(hi));
  return r;
}
static __device__ __forceinline__ float clipc(float a) { return fminf(fmaxf(a, -FCAP), FCAP); }

// pack 8 consecutive f32 into one bf16x8 fragment (RNE)
static __device__ __forceinline__ bf16x8 mkfrag(const float* __restrict__ p) {
  f32x4 a = *(const f32x4*)p, b = *(const f32x4*)(p + 4);
  u32x4 wv = {pk2(a[0], a[1]), pk2(a[2], a[3]), pk2(b[0], b[1]), pk2(b[2], b[3])};
  return __builtin_bit_cast(bf16x8, wv);
}

#define MFMA16(A, B, C) __builtin_amdgcn_mfma_f32_16x16x32_bf16(A, B, C, 0, 0, 0)

// leaky_relu on 4 packed f32: v_pk_mul_f32 + v_pk_max_f32
static __device__ __forceinline__ f32x4 lrelu4(f32x4 v) {
  return __builtin_elementwise_max(v, v * 0.01f);
}

// 16x16x32 bf16 layouts (HW-verified rounds 3/5):
//   A: row = lane&15, k = 32*kt + 8*(lane>>4) + e
//   B: col = lane&15, k = 32*kt + 8*(lane>>4) + e
//   C: col = lane&15, row = 4*(lane>>4) + reg
// LDS h-buffer: buf[col][kpair] (u32 = bf16x2 of rows 2kp,2kp+1), row stride 68
// words. Per-quarter bank check (b128 granule = 16 lanes): group = (c+g+4kt)&7
// -> 2 lanes (c, c+8) per group = 2-way = free (m136). fbuf stride 20 words:
// group of float4 read at 20c = (5c)&7, bijective in c&7 -> 2-way = free
// (stride 8 was 4-way: 9.16M conflict cycles in round 5).

// 512 WGs x 256 threads (2 WGs/CU, 2 waves/SIMD). Each WG: 16 particles.
// Wave wv owns hidden rows [32wv, 32wv+32) as two 16-row M-tiles.
__global__ __launch_bounds__(256, 2) void ode_kernel(
    const float* __restrict__ ts, const float* __restrict__ y0,
    const float* __restrict__ W1, const float* __restrict__ b1,
    const float* __restrict__ W2, const float* __restrict__ b2,
    const float* __restrict__ W3, const float* __restrict__ b3,
    const float* __restrict__ W4, const float* __restrict__ b4,
    float* __restrict__ out) {
  const int tid = threadIdx.x;
  const int wv = __builtin_amdgcn_readfirstlane(tid >> 6);  // wave 0..3
  const int l = tid & 63;
  const int g = l >> 4;   // lane group 0..3
  const int c = l & 15;   // particle col / A-row-local
  const int gp0 = blockIdx.x * 16;

  __shared__ alignas(16) u32 bufA[16 * 68];
  __shared__ alignas(16) u32 bufB[16 * 68];
  __shared__ alignas(16) float fbuf[16 * 20];  // [c][wv][2] @ stride 20

  // ---- A-fragments (one-time, f32 -> bf16 RNE) ----
  bf16x8 aW2[2][4], aW3[2][4];
#pragma unroll
  for (int mt = 0; mt < 2; ++mt) {
    const int R = 32 * wv + 16 * mt + c;
#pragma unroll
    for (int kt = 0; kt < 4; ++kt) {
      aW2[mt][kt] = mkfrag(W2 + R * 128 + 32 * kt + 8 * g);
      aW3[mt][kt] = mkfrag(W3 + R * 128 + 32 * kt + 8 * g);
    }
  }
  // L1: k0,k1 = W1 row, k2 = b1 (B supplies y1,y2,1)
  bf16x8 aW1[2];
#pragma unroll
  for (int mt = 0; mt < 2; ++mt) {
    const int R = 32 * wv + 16 * mt + c;
    u32x4 f = {0, 0, 0, 0};
    if (g == 0) {
      f[0] = pk2(W1[2 * R], W1[2 * R + 1]);
      f[1] = pk2(b1[R], 0.f);
    }
    aW1[mt] = __builtin_bit_cast(bf16x8, f);
  }
  // L4: A rows 0,1 = W4 over this wave's k-range [32wv, 32wv+32)
  bf16x8 aW4;
  {
    u32x4 f = {0, 0, 0, 0};
    if (c < 2) {
      const float* s = W4 + c * 128 + 32 * wv + 8 * g;
      f32x4 a = *(const f32x4*)s, b = *(const f32x4*)(s + 4);
      f = (u32x4){pk2(a[0], a[1]), pk2(a[2], a[3]), pk2(b[0], b[1]), pk2(b[2], b[3])};
    }
    aW4 = __builtin_bit_cast(bf16x8, f);
  }
  // b2/b3 as C-init registers: C row = 32wv + 16mt + 4g + reg
  f32x4 cb2[2], cb3[2];
#pragma unroll
  for (int mt = 0; mt < 2; ++mt) {
#pragma unroll
    for (int r = 0; r < 4; ++r) {
      const int row = 32 * wv + 16 * mt + 4 * g + r;
      cb2[mt][r] = b2[row];
      cb3[mt][r] = b3[row];
    }
  }
  const float b40 = b4[0], b41 = b4[1];

  // ---- state: all lanes track y for col c (uniform across g, wv) ----
  float y1 = y0[(gp0 + c) * 2];
  float y2 = y0[(gp0 + c) * 2 + 1];

  if (wv == 0 && g == 0) {
    float2 st = {clipc(y1), clipc(y2)};
    *(float2*)(out + (gp0 + c) * 2) = st;
  }

  const f32x4 zero4 = {0.f, 0.f, 0.f, 0.f};
  const int wbase = 68 * c + 16 * wv + 2 * g;  // write word base (M-tile 0)
  const int rbase = 68 * c + 4 * g;            // read word base (k-tile 0)

#pragma unroll 1
  for (int t = 0; t < NT - 1; ++t) {
    const float dt = ts[t + 1] - ts[t];

    // ---- layer 1 (bias fused: B k0=y1,k1=y2,k2=1) ----
    u32x4 byw = {0, 0, 0, 0};
    if (g == 0) {
      byw[0] = pk2(y1, y2);
      byw[1] = 0x3f80u;  // bf16(1.0) in lo half
    }
    const bf16x8 By = __builtin_bit_cast(bf16x8, byw);
    f32x4 C0 = lrelu4(MFMA16(aW1[0], By, zero4));
    f32x4 C1 = lrelu4(MFMA16(aW1[1], By, zero4));
    *(__shared__ u32x2*)&bufA[wbase]     = (u32x2){pk2(C0[0], C0[1]), pk2(C0[2], C0[3])};
    *(__shared__ u32x2*)&bufA[wbase + 8] = (u32x2){pk2(C1[0], C1[1]), pk2(C1[2], C1[3])};
    __syncthreads();

    // ---- layer 2 (4 independent 2-deep MFMA chains) ----
    {
      const bf16x8 q0 = __builtin_bit_cast(bf16x8, *(const __shared__ u32x4*)&bufA[rbase]);
      const bf16x8 q1 = __builtin_bit_cast(bf16x8, *(const __shared__ u32x4*)&bufA[rbase + 16]);
      const bf16x8 q2 = __builtin_bit_cast(bf16x8, *(const __shared__ u32x4*)&bufA[rbase + 32]);
      const bf16x8 q3 = __builtin_bit_cast(bf16x8, *(const __shared__ u32x4*)&bufA[rbase + 48]);
      f32x4 D0 = MFMA16(aW2[0][0], q0, cb2[0]);
      f32x4 D1 = MFMA16(aW2[1][0], q0, cb2[1]);
      f32x4 E0 = MFMA16(aW2[0][1], q1, zero4);
      f32x4 E1 = MFMA16(aW2[1][1], q1, zero4);
      D0 = MFMA16(aW2[0][2], q2, D0);
      D1 = MFMA16(aW2[1][2], q2, D1);
      E0 = MFMA16(aW2[0][3], q3, E0);
      E1 = MFMA16(aW2[1][3], q3, E1);
      C0 = lrelu4(D0 + E0);
      C1 = lrelu4(D1 + E1);
    }
    *(__shared__ u32x2*)&bufB[wbase]     = (u32x2){pk2(C0[0], C0[1]), pk2(C0[2], C0[3])};
    *(__shared__ u32x2*)&bufB[wbase + 8] = (u32x2){pk2(C1[0], C1[1]), pk2(C1[2], C1[3])};
    __syncthreads();

    // ---- layer 3 (h3 -> bufA; safe: all waves past their L2 reads) ----
    {
      const bf16x8 q0 = __builtin_bit_cast(bf16x8, *(const __shared__ u32x4*)&bufB[rbase]);
      const bf16x8 q1 = __builtin_bit_cast(bf16x8, *(const __shared__ u32x4*)&bufB[rbase + 16]);
      const bf16x8 q2 = __builtin_bit_cast(bf16x8, *(const __shared__ u32x4*)&bufB[rbase + 32]);
      const bf16x8 q3 = __builtin_bit_cast(bf16x8, *(const __shared__ u32x4*)&bufB[rbase + 48]);
      f32x4 D0 = MFMA16(aW3[0][0], q0, cb3[0]);
      f32x4 D1 = MFMA16(aW3[1][0], q0, cb3[1]);
      f32x4 E0 = MFMA16(aW3[0][1], q1, zero4);
      f32x4 E1 = MFMA16(aW3[1][1], q1, zero4);
      D0 = MFMA16(aW3[0][2], q2, D0);
      D1 = MFMA16(aW3[1][2], q2, D1);
      E0 = MFMA16(aW3[0][3], q3, E0);
      E1 = MFMA16(aW3[1][3], q3, E1);
      C0 = lrelu4(D0 + E0);
      C1 = lrelu4(D1 + E1);
    }
    *(__shared__ u32x2*)&bufA[wbase]     = (u32x2){pk2(C0[0], C0[1]), pk2(C0[2], C0[3])};
    *(__shared__ u32x2*)&bufA[wbase + 8] = (u32x2){pk2(C1[0], C1[1]), pk2(C1[2], C1[3])};

    // ---- layer 4: k-tile wv is self-owned -> no barrier, just lgkmcnt ----
    const bf16x8 q3v =
        __builtin_bit_cast(bf16x8, *(const __shared__ u32x4*)&bufA[rbase + 16 * wv]);
    f32x4 C4 = MFMA16(aW4, q3v, zero4);
    if (g == 0)
      *(__shared__ float2*)&fbuf[c * 20 + wv * 2] = (float2){C4[0], C4[1]};
    __syncthreads();

    // ---- reduce 4 wave-partials + Euler update (uniform across lanes) ----
    const f32x4 pa = *(const __shared__ f32x4*)&fbuf[c * 20];
    const f32x4 pb = *(const __shared__ f32x4*)&fbuf[c * 20 + 4];
    const f32x4 s = pa + pb;  // v_pk_add_f32
    const float f0 = b40 + s[0] + s[2];
    const float f1v = b41 + s[1] + s[3];
    y1 += dt * (f0 - y1);
    y2 += dt * (f1v - y2);

    if (wv == 0 && g == 0) {
      float2 st = {clipc(y1), clipc(y2)};
      *(float2*)(out + (t + 1) * (NB * 2) + (gp0 + c) * 2) = st;
    }
  }
}

extern "C" void kernel_launch(void* const* d_in, const int* in_sizes, int n_in,
                              void* d_out, int out_size, void* d_ws, size_t ws_size,
                              hipStream_t stream) {
  const float* ts = (const float*)d_in[0];
  const float* y0 = (const float*)d_in[1];
  const float* W1 = (const float*)d_in[2];
  const float* b1 = (const float*)d_in[3];
  const float* W2 = (const float*)d_in[4];
  const float* b2 = (const float*)d_in[5];
  const float* W3 = (const float*)d_in[6];
  const float* b3 = (const float*)d_in[7];
  const float* W4 = (const float*)d_in[8];
  const float* b4 = (const float*)d_in[9];

  ode_kernel<<<NB / 16, 256, 0, stream>>>(ts, y0, W1, b1, W2, b2, W3, b3, W4, b4,
                                          (float*)d_out);
}